// Round 10
// baseline (1079.458 us; speedup 1.0000x reference)
//
#include <hip/hip_runtime.h>

typedef unsigned short u16;
typedef unsigned int u32;
typedef __attribute__((ext_vector_type(8))) _Float16 f16x8;  // 8 fp16 = 4 VGPRs
typedef __attribute__((ext_vector_type(4))) float f32x4;
typedef __attribute__((ext_vector_type(8))) u16 u16x8;

#define N_NODES 20000
#define N_EDGES 320000
#define F_IN 128
#define HID 256
#define OUT_F 32
#define N_LAYERS 30
#define N_GRAPHS 16
#define ELLCAP 64

// ---------------- fp16 helpers ----------------
__device__ __forceinline__ float h2f(u16 u) {
    _Float16 h;
    __builtin_memcpy(&h, &u, 2);
    return (float)h;
}
__device__ __forceinline__ u16 f2h(float f) {
    _Float16 h = (_Float16)f;
    u16 u;
    __builtin_memcpy(&u, &h, 2);
    return u;
}

__device__ __forceinline__ void gl_lds16(const u16* g, u16* l) {
    __builtin_amdgcn_global_load_lds((const u32*)g, (u32*)l, 16, 0, 0);
}

// ---------------- graph build ----------------
// fill_ell also produces the degree: cursor's final value == in-degree at dst.
// ell_col is pre-zeroed; unfilled slots stay 0 (node 0: valid, masked off in agg).
__global__ void fill_ell_kernel(const int* __restrict__ src, const int* __restrict__ dst,
                                int* __restrict__ cursor, u16* __restrict__ ell_col, int E) {
    int e = blockIdx.x * blockDim.x + threadIdx.x;
    if (e >= E) return;
    int s = src[e], d = dst[e];
    int slot = atomicAdd(&cursor[d], 1);
    if (slot < ELLCAP) ell_col[d * ELLCAP + slot] = (u16)s;
}

__global__ void dinv_kernel(const int* __restrict__ cnt, float* __restrict__ dinv, int n) {
    int i = blockIdx.x * blockDim.x + threadIdx.x;
    if (i < n) dinv[i] = rsqrtf((float)(cnt[i] + 1));  // +1 self loop
}

// x' = fp16(dinv ⊙ x): layer-1 gather source (fp16 = the measured numerics floor;
// fp8 failed at 9.3e-6 vs threshold 1.86e-7, R4)
__global__ void prescale_x_kernel(const float* __restrict__ x, const int* __restrict__ cnt,
                                  u16* __restrict__ xs, int total) {
    int i = blockIdx.x * 256 + threadIdx.x;
    if (i < total) xs[i] = f2h(x[i] * rsqrtf((float)(cnt[i >> 7] + 1)));   // F_IN = 128
}

// ---------------- degree sort (R10): counting sort by clamped degree ----------------
// Wave divergence: a gather wave carries 8 nodes and runs max(nb of 8) batch
// iterations (Poisson(16) -> max-of-8 ~1.4x mean; tail nodes drag waves to 8-9).
// perm groups degree-homogeneous nodes -> max ~= mean. Within-bucket order is
// nondeterministic (atomics) but each node's accumulation chain is independent
// and written to its own row -> results bit-identical.
__global__ void hist_kernel(const int* __restrict__ cnt, int* __restrict__ hist, int n) {
    int i = blockIdx.x * blockDim.x + threadIdx.x;
    if (i >= n) return;
    int k = cnt[i]; k = k < ELLCAP ? k : ELLCAP;
    atomicAdd(&hist[k], 1);
}
__global__ void scan_kernel(const int* __restrict__ hist, int* __restrict__ cur) {
    if (threadIdx.x == 0) {
        int s = 0;
        for (int i = 0; i <= ELLCAP; ++i) { cur[i] = s; s += hist[i]; }
    }
}
__global__ void scatter_kernel(const int* __restrict__ cnt, int* __restrict__ cur,
                               int* __restrict__ perm, int n) {
    int i = blockIdx.x * blockDim.x + threadIdx.x;
    if (i >= n) return;
    int k = cnt[i]; k = k < ELLCAP ? k : ELLCAP;
    perm[atomicAdd(&cur[k], 1)] = i;
}

// ---------------- weight transpose to fp16 (LDS-tiled, coalesced writes) ----------------
// W [L][K][N] (f32) -> T [L][N][K] (fp16); 32x32 tiles.
__global__ __launch_bounds__(256) void transpose_f16_tiled(const float* __restrict__ W,
                                                           u16* __restrict__ T,
                                                           int K, int N) {
    __shared__ float tile[32][33];
    const int l = blockIdx.y;
    const int ntn = N >> 5;
    const int kt = blockIdx.x / ntn, ntile = blockIdx.x % ntn;
    const float* Wl = W + (size_t)l * K * N;
    u16* Tl = T + (size_t)l * K * N;
    const int r8 = threadIdx.x >> 5, c = threadIdx.x & 31;
    #pragma unroll
    for (int rr = 0; rr < 4; ++rr) {
        int r = rr * 8 + r8;
        tile[r][c] = Wl[(size_t)(kt * 32 + r) * N + ntile * 32 + c];
    }
    __syncthreads();
    #pragma unroll
    for (int rr = 0; rr < 4; ++rr) {
        int n = rr * 8 + r8;                 // transposed row (N dim)
        float v = tile[c][n];                // W[k=kt*32+c][n]
        Tl[(size_t)(ntile * 32 + n) * K + kt * 32 + c] = f2h(v);
    }
}

// ---------------- fused layer (R10 = R6/R8 structure + degree-sorted node groups) ----------------
// One kernel per GCN layer. Block = 32 permuted nodes, 256 threads (4 waves). Grid = 625.
// Structure lineage (measured): R6 bulk-gather + Bs-staged GEMM = 930.9us (best);
// R7 fine interleave = 1301 (barrier serialization + VGPR choke); R9 direct-B = 1077
// (scattered L2 requests beat by coalesced global_load_lds staging). R10 keeps R6's
// structure and attacks gather WAVE DIVERGENCE via the degree-sort perm.
// NUMERICS: per-node accumulation order (self -> batches asc -> masked tail), GEMM
// k/kk/mt/nt order, bias/rowscale values all unchanged -> absmax must be exactly
// 1.490116e-07; deviation = bug.
template <int K>
__global__ __launch_bounds__(256, 3) void layer_fused(const u16* __restrict__ hs,
                                                      const u16* __restrict__ B,
                                                      const u16* __restrict__ ell_col,
                                                      const int* __restrict__ cnt,
                                                      const float* __restrict__ dinv,
                                                      const float* __restrict__ bias,
                                                      const float* __restrict__ rowscale,
                                                      const int* __restrict__ perm,
                                                      u16* __restrict__ Ch,
                                                      float* __restrict__ C) {
    __shared__ u16 cols[32 * ELLCAP];                 // 4 KB
    __shared__ __align__(16) u16 gs[32 * HID];        // 16 KB: A-operand (32*K), then fp16 out-stage
    __shared__ __align__(16) u16 Bs[256 * 64];        // 32 KB: B n-major [256][64k], then f32 out-stage
    __shared__ int pnode[32];
    const int node0 = blockIdx.x * 32;
    const int tid = threadIdx.x;
    const int nd = tid >> 3, sub = tid & 7;
    const int node = perm[node0 + nd];                 // degree-sorted group
    if (sub == 0) pnode[nd] = node;
    *(u16x8*)&cols[nd * ELLCAP + sub * 8] = *(const u16x8*)&ell_col[(size_t)node * ELLCAP + sub * 8];
    int c = cnt[node]; c = c < ELLCAP ? c : ELLCAP;
    const float dd = dinv[node];
    __syncthreads();                                   // cols + pnode staged
    const u16* cl = &cols[nd * ELLCAP];
    const int nb = (c + 7) >> 3;                       // 8-batches (last masked)
    constexpr int S = K / 64;                          // slices

    // ---- phase 1: aggregate into gs (R6 order: slices natural, self -> batches) ----
    #pragma unroll 1
    for (int p = 0; p < S; ++p) {
        const int f = p * 64 + sub * 8;
        f32x4 a0 = {}, a1 = {};
        {   // self loop (pre-scaled)
            u16x8 sv = *(const u16x8*)(hs + (size_t)node * K + f);
            #pragma unroll
            for (int i = 0; i < 4; ++i) a0[i] += h2f(sv[i]);
            #pragma unroll
            for (int i = 0; i < 4; ++i) a1[i] += h2f(sv[i + 4]);
        }
        if (nb > 0) {
            u16x8 vbuf[8];
            u16x8 cc = *(const u16x8*)&cl[0];
            #pragma unroll
            for (int j = 0; j < 8; ++j) vbuf[j] = *(const u16x8*)(hs + (size_t)cc[j] * K + f);
            int base = 0;
            for (int b = 1; b < nb; ++b) {
                u16x8 cn = *(const u16x8*)&cl[b * 8];
                u16x8 vn[8];
                #pragma unroll
                for (int j = 0; j < 8; ++j) vn[j] = *(const u16x8*)(hs + (size_t)cn[j] * K + f);
                #pragma unroll
                for (int j = 0; j < 8; ++j) {
                    #pragma unroll
                    for (int i = 0; i < 4; ++i) a0[i] += h2f(vbuf[j][i]);
                    #pragma unroll
                    for (int i = 0; i < 4; ++i) a1[i] += h2f(vbuf[j][i + 4]);
                }
                base += 8;
                #pragma unroll
                for (int j = 0; j < 8; ++j) vbuf[j] = vn[j];
            }
            const u16x8 zz = {};
            #pragma unroll
            for (int j = 0; j < 8; ++j) {
                u16x8 v = (base + j < c) ? vbuf[j] : zz;   // masked final batch
                #pragma unroll
                for (int i = 0; i < 4; ++i) a0[i] += h2f(v[i]);
                #pragma unroll
                for (int i = 0; i < 4; ++i) a1[i] += h2f(v[i + 4]);
            }
        }
        u16x8 o;
        #pragma unroll
        for (int i = 0; i < 4; ++i) o[i] = f2h(a0[i] * dd);
        #pragma unroll
        for (int i = 0; i < 4; ++i) o[i + 4] = f2h(a1[i] * dd);
        const int cc_ = p * 8 + sub;                   // global 8-elem chunk index
        *(u16x8*)&gs[nd * K + ((cc_ ^ (nd & 7)) << 3)] = o;
    }

    // ---- phase 2: GEMM (R6 verbatim: Bs staged via global_load_lds) ----
    const int wave = tid >> 6, lane = tid & 63;
    const int lr = lane >> 3, lc = lane & 7;
    #pragma unroll
    for (int q = 0; q < 8; ++q) {
        int rl = (wave * 8 + q) * 8 + lr;              // B row (n), 0..255
        gl_lds16(B + (size_t)rl * K + ((lc ^ (rl & 7)) << 3), &Bs[(wave * 8 + q) * 512]);
    }
    f32x4 acc[2][4] = {};
    #pragma unroll
    for (int k = 0; k < S; ++k) {
        __syncthreads();                               // gs + Bs(k) ready (drains vmcnt)
        const int k0 = k * 64;
        #pragma unroll
        for (int kk = 0; kk < 2; ++kk) {
            const int c8 = kk * 4 + (lane >> 4);       // chunk within 64-k tile, 0..7
            f16x8 bf[4];
            #pragma unroll
            for (int nt = 0; nt < 4; ++nt) {
                int n = wave * 64 + nt * 16 + (lane & 15);
                bf[nt] = *(const f16x8*)&Bs[n * 64 + ((c8 ^ (n & 7)) << 3)];
            }
            #pragma unroll
            for (int mt = 0; mt < 2; ++mt) {
                int ml = mt * 16 + (lane & 15);
                int cg = (k0 >> 3) + c8;               // global chunk index
                f16x8 af = *(const f16x8*)&gs[ml * K + ((cg ^ (ml & 7)) << 3)];
                #pragma unroll
                for (int nt = 0; nt < 4; ++nt)
                    acc[mt][nt] = __builtin_amdgcn_mfma_f32_16x16x32_f16(af, bf[nt], acc[mt][nt], 0, 0, 0);
            }
        }
        if (k + 1 < S) {
            __syncthreads();                           // all waves done reading Bs(k)
            const int kn = k0 + 64;
            #pragma unroll
            for (int q = 0; q < 8; ++q) {
                int rl = (wave * 8 + q) * 8 + lr;
                gl_lds16(B + (size_t)rl * K + kn + ((lc ^ (rl & 7)) << 3), &Bs[(wave * 8 + q) * 512]);
            }
        }
    }
    // ---- epilogue: bias + relu (+ rowscale); LDS-staged, full-line writes to
    // permuted rows (R8's packed path — load-bearing now that rows scatter).
    // C/D layout col=lane&15, row=(lane>>4)*4+r. Values identical to R6/R8.
    __syncthreads();                                   // all GEMM reads of gs/Bs done
    if (Ch) {
        #pragma unroll
        for (int mt = 0; mt < 2; ++mt) {
            #pragma unroll
            for (int r = 0; r < 4; ++r) {
                int lrow = mt * 16 + ((lane >> 4) << 2) + r;
                float sc = rowscale ? rowscale[pnode[lrow]] : 1.f;
                #pragma unroll
                for (int nt = 0; nt < 4; ++nt) {
                    int gc = wave * 64 + nt * 16 + (lane & 15);
                    float v = sc * fmaxf(acc[mt][nt][r] + bias[gc], 0.f);
                    gs[lrow * HID + (gc ^ ((lrow & 7) << 3))] = f2h(v);
                }
            }
        }
        __syncthreads();
        const int row = tid >> 3, colb = (tid & 7) * 32;
        const size_t prow = (size_t)pnode[row];
        #pragma unroll
        for (int j = 0; j < 4; ++j) {
            int cs = (colb + j * 8) ^ ((row & 7) << 3);
            *(u16x8*)(Ch + prow * HID + colb + j * 8) = *(const u16x8*)&gs[row * HID + cs];
        }
    } else {
        float* Bf = (float*)Bs;                        // 32 KB = 32 x 256 f32, exact
        #pragma unroll
        for (int mt = 0; mt < 2; ++mt) {
            #pragma unroll
            for (int r = 0; r < 4; ++r) {
                int lrow = mt * 16 + ((lane >> 4) << 2) + r;
                float sc = rowscale ? rowscale[pnode[lrow]] : 1.f;
                #pragma unroll
                for (int nt = 0; nt < 4; ++nt) {
                    int gc = wave * 64 + nt * 16 + (lane & 15);
                    float v = sc * fmaxf(acc[mt][nt][r] + bias[gc], 0.f);
                    Bf[lrow * HID + (gc ^ ((lrow & 7) << 2))] = v;
                }
            }
        }
        __syncthreads();
        const int row = tid >> 3, colb = (tid & 7) * 32;
        const size_t prow = (size_t)pnode[row];
        #pragma unroll
        for (int j = 0; j < 8; ++j) {
            int cs = (colb + j * 4) ^ ((row & 7) << 2);
            *(f32x4*)(C + prow * HID + colb + j * 4) = *(const f32x4*)&Bf[row * HID + cs];
        }
    }
}

// ---------------- pooling ----------------
#define POOL_CHUNK 32
__global__ __launch_bounds__(256) void pool_kernel(const float* __restrict__ h,
                                                   const int* __restrict__ batch,
                                                   float* __restrict__ pool_sum) {
    int f = threadIdx.x;
    int start = blockIdx.x * POOL_CHUNK;
    int end = start + POOL_CHUNK; end = end < N_NODES ? end : N_NODES;
    if (start >= N_NODES) return;
    int gcur = batch[start];
    float acc = 0.f;
    for (int i = start; i < end; ++i) {
        int g = batch[i];
        if (g != gcur) { atomicAdd(&pool_sum[gcur * HID + f], acc); acc = 0.f; gcur = g; }
        acc += h[(size_t)i * HID + f];
    }
    atomicAdd(&pool_sum[gcur * HID + f], acc);
}

__device__ int lb_int(const int* __restrict__ a, int n, int v) {
    int lo = 0, hi = n;
    while (lo < hi) {
        int mid = (lo + hi) >> 1;
        if (a[mid] < v) lo = mid + 1; else hi = mid;
    }
    return lo;
}

__global__ void final_linear_kernel(const float* __restrict__ pool_sum,
                                    const int* __restrict__ batch,
                                    const float* __restrict__ Wlin,
                                    const float* __restrict__ blin,
                                    float* __restrict__ out) {
    int idx = blockIdx.x * blockDim.x + threadIdx.x;
    if (idx >= N_GRAPHS * OUT_F) return;
    int g = idx / OUT_F, o = idx % OUT_F;
    int lo = lb_int(batch, N_NODES, g);
    int hi = lb_int(batch, N_NODES, g + 1);
    float cinv = 1.f / fmaxf((float)(hi - lo), 1.f);
    float s = blin[o];
    for (int k = 0; k < HID; ++k) s += (pool_sum[g * HID + k] * cinv) * Wlin[k * OUT_F + o];
    out[idx] = s;
}

// ---------------- launch ----------------
static inline size_t align_up(size_t x, size_t a) { return (x + a - 1) & ~(a - 1); }

extern "C" void kernel_launch(void* const* d_in, const int* in_sizes, int n_in,
                              void* d_out, int out_size, void* d_ws, size_t ws_size,
                              hipStream_t stream) {
    const float* x     = (const float*)d_in[0];
    const int*   elist = (const int*)d_in[1];   // [2, E]
    const int*   batch = (const int*)d_in[2];
    const float* W1    = (const float*)d_in[3];
    const float* b1    = (const float*)d_in[4];
    const float* Wm    = (const float*)d_in[5];
    const float* bm    = (const float*)d_in[6];
    const float* Wlin  = (const float*)d_in[7];
    const float* blin  = (const float*)d_in[8];
    float* outp = (float*)d_out;

    const int* srcA = elist;
    const int* dstA = elist + N_EDGES;

    char* ws = (char*)d_ws;
    size_t off = 0;
    float* h      = (float*)(ws + off); off = align_up(off + sizeof(float) * N_NODES * HID, 1024);
    u16*   hA     = (u16*)(ws + off);   off = align_up(off + sizeof(u16) * N_NODES * HID, 1024);
    u16*   hB     = (u16*)(ws + off);   off = align_up(off + sizeof(u16) * N_NODES * HID, 1024);
    u16*   xs     = (u16*)(ws + off);   off = align_up(off + sizeof(u16) * N_NODES * F_IN, 1024);
    u16*   W1T    = (u16*)(ws + off);   off = align_up(off + sizeof(u16) * F_IN * HID, 1024);
    u16*   WmT    = (u16*)(ws + off);   off = align_up(off + sizeof(u16) * (N_LAYERS - 1) * HID * HID, 1024);
    int*   cursor = (int*)(ws + off);   off = align_up(off + sizeof(int) * N_NODES, 1024);
    float* dinv   = (float*)(ws + off); off = align_up(off + sizeof(float) * N_NODES, 1024);
    u16*   ell_col = (u16*)(ws + off);  off = align_up(off + sizeof(u16) * N_NODES * ELLCAP, 1024);
    float* pool_sum = (float*)(ws + off); off = align_up(off + sizeof(float) * N_GRAPHS * HID, 1024);
    int*   perm   = (int*)(ws + off);   off = align_up(off + sizeof(int) * N_NODES, 1024);
    int*   hist   = (int*)(ws + off);   off = align_up(off + sizeof(int) * (ELLCAP + 1), 1024);
    int*   buckcur = (int*)(ws + off);  off = align_up(off + sizeof(int) * (ELLCAP + 1), 1024);

    hipMemsetAsync(cursor, 0, sizeof(int) * N_NODES, stream);
    hipMemsetAsync(ell_col, 0, sizeof(u16) * N_NODES * ELLCAP, stream);  // pad slots -> node 0 (masked)
    hipMemsetAsync(pool_sum, 0, sizeof(float) * N_GRAPHS * HID, stream);
    hipMemsetAsync(hist, 0, sizeof(int) * (ELLCAP + 1), stream);

    fill_ell_kernel<<<(N_EDGES + 255) / 256, 256, 0, stream>>>(srcA, dstA, cursor, ell_col, N_EDGES);
    dinv_kernel<<<(N_NODES + 255) / 256, 256, 0, stream>>>(cursor, dinv, N_NODES);
    prescale_x_kernel<<<(N_NODES * F_IN + 255) / 256, 256, 0, stream>>>(x, cursor, xs, N_NODES * F_IN);
    // degree sort: histogram -> scan -> scatter
    hist_kernel<<<(N_NODES + 255) / 256, 256, 0, stream>>>(cursor, hist, N_NODES);
    scan_kernel<<<1, 64, 0, stream>>>(hist, buckcur);
    scatter_kernel<<<(N_NODES + 255) / 256, 256, 0, stream>>>(cursor, buckcur, perm, N_NODES);

    transpose_f16_tiled<<<dim3((F_IN / 32) * (HID / 32), 1), 256, 0, stream>>>(W1, W1T, F_IN, HID);
    transpose_f16_tiled<<<dim3((HID / 32) * (HID / 32), N_LAYERS - 1), 256, 0, stream>>>(Wm, WmT, HID, HID);

    const int lgrid = N_NODES / 32;   // 625, exact
    // layer 1: K = F_IN, gather from xs, write fp16 hA (double-buffer ping-pong after)
    layer_fused<F_IN><<<lgrid, 256, 0, stream>>>(xs, W1T, ell_col, cursor, dinv, b1, dinv, perm, hA, h);
    u16* cur = hA; u16* nxt = hB;
    for (int l = 0; l < N_LAYERS - 1; ++l) {
        const bool last = (l == N_LAYERS - 2);
        layer_fused<HID><<<lgrid, 256, 0, stream>>>(cur, WmT + (size_t)l * HID * HID,
                                                    ell_col, cursor, dinv,
                                                    bm + (size_t)l * HID,
                                                    last ? nullptr : dinv, perm,
                                                    last ? nullptr : nxt, h);
        u16* t = cur; cur = nxt; nxt = t;
    }
    pool_kernel<<<(N_NODES + POOL_CHUNK - 1) / POOL_CHUNK, 256, 0, stream>>>(h, batch, pool_sum);
    final_linear_kernel<<<2, 256, 0, stream>>>(pool_sum, batch, Wlin, blin, outp);
}

// Round 12
// 952.513 us; speedup vs baseline: 1.1333x; 1.1333x over previous
//
#include <hip/hip_runtime.h>

typedef unsigned short u16;
typedef unsigned int u32;
typedef __attribute__((ext_vector_type(8))) _Float16 f16x8;  // 8 fp16 = 4 VGPRs
typedef __attribute__((ext_vector_type(4))) float f32x4;
typedef __attribute__((ext_vector_type(8))) u16 u16x8;

#define N_NODES 20000
#define N_EDGES 320000
#define F_IN 128
#define HID 256
#define OUT_F 32
#define N_LAYERS 30
#define N_GRAPHS 16
#define ELLCAP 64

// ---------------- fp16 helpers ----------------
__device__ __forceinline__ float h2f(u16 u) {
    _Float16 h;
    __builtin_memcpy(&h, &u, 2);
    return (float)h;
}
__device__ __forceinline__ u16 f2h(float f) {
    _Float16 h = (_Float16)f;
    u16 u;
    __builtin_memcpy(&u, &h, 2);
    return u;
}

__device__ __forceinline__ void gl_lds16(const u16* g, u16* l) {
    __builtin_amdgcn_global_load_lds((const u32*)g, (u32*)l, 16, 0, 0);
}

// ---------------- graph build ----------------
// fill_ell also produces the degree: cursor's final value == in-degree at dst.
// ell_col is pre-zeroed; unfilled slots stay 0 (node 0: valid, masked off in agg).
__global__ void fill_ell_kernel(const int* __restrict__ src, const int* __restrict__ dst,
                                int* __restrict__ cursor, u16* __restrict__ ell_col, int E) {
    int e = blockIdx.x * blockDim.x + threadIdx.x;
    if (e >= E) return;
    int s = src[e], d = dst[e];
    int slot = atomicAdd(&cursor[d], 1);
    if (slot < ELLCAP) ell_col[d * ELLCAP + slot] = (u16)s;
}

__global__ void dinv_kernel(const int* __restrict__ cnt, float* __restrict__ dinv, int n) {
    int i = blockIdx.x * blockDim.x + threadIdx.x;
    if (i < n) dinv[i] = rsqrtf((float)(cnt[i] + 1));  // +1 self loop
}

// x' = fp16(dinv ⊙ x): layer-1 gather source (fp16 = the measured numerics floor;
// fp8 failed R4)
__global__ void prescale_x_kernel(const float* __restrict__ x, const int* __restrict__ cnt,
                                  u16* __restrict__ xs, int total) {
    int i = blockIdx.x * 256 + threadIdx.x;
    if (i < total) xs[i] = f2h(x[i] * rsqrtf((float)(cnt[i >> 7] + 1)));   // F_IN = 128
}

// ---------------- weight transpose to fp16 (LDS-tiled, coalesced writes) ----------------
// W [L][K][N] (f32) -> T [L][N][K] (fp16); 32x32 tiles.
__global__ __launch_bounds__(256) void transpose_f16_tiled(const float* __restrict__ W,
                                                           u16* __restrict__ T,
                                                           int K, int N) {
    __shared__ float tile[32][33];
    const int l = blockIdx.y;
    const int ntn = N >> 5;
    const int kt = blockIdx.x / ntn, ntile = blockIdx.x % ntn;
    const float* Wl = W + (size_t)l * K * N;
    u16* Tl = T + (size_t)l * K * N;
    const int r8 = threadIdx.x >> 5, c = threadIdx.x & 31;
    #pragma unroll
    for (int rr = 0; rr < 4; ++rr) {
        int r = rr * 8 + r8;
        tile[r][c] = Wl[(size_t)(kt * 32 + r) * N + ntile * 32 + c];
    }
    __syncthreads();
    #pragma unroll
    for (int rr = 0; rr < 4; ++rr) {
        int n = rr * 8 + r8;                 // transposed row (N dim)
        float v = tile[c][n];                // W[k=kt*32+c][n]
        Tl[(size_t)(ntile * 32 + n) * K + kt * 32 + c] = f2h(v);
    }
}

// ---------------- fused layer (R12 = R6 + double-buffered 32-k Bs, overlapped staging) ----------------
// One kernel per GCN layer. Block = 32 nodes, 256 threads (4 waves). Grid = 625.
// Lineage (measured): R6 bulk = 930.9 BEST; R7 interleave 1301; R9 direct-B 1077;
// R10 degree-sort 1079 (sort overhead, divergence null); R11 cooperative = launch
// rejected under graph capture (output never written).
// R6's leak: stage(k+1) was issued AFTER MFMA(k) and immediately drained by the
// next __syncthreads (vmcnt(0)) -> all 4 B-stages/layer fully latency-exposed.
// R12: Bs double-buffered as 2 x [256 n][32 k] (16KB each):
//   - tile 0 staged BEFORE the gather (no barrier between) -> hidden under ~16us.
//   - in-loop: barrier -> stage(k+1) into idle buffer -> MFMA(k) from ready buffer;
//     loads overlap the MFMAs, drained by the NEXT iteration's barrier.
// Barrier count unchanged (8/layer, plain __syncthreads -> race-free).
// NUMERICS: gather (R6 verbatim) and MFMA sequence over (k-chunk, mt, nt) identical
// (k'=2k+kk mapping) -> absmax must be exactly 1.490116e-07; deviation = bug.
template <int K>
__global__ __launch_bounds__(256, 3) void layer_fused(const u16* __restrict__ hs,
                                                      const u16* __restrict__ B,
                                                      const u16* __restrict__ ell_col,
                                                      const int* __restrict__ cnt,
                                                      const float* __restrict__ dinv,
                                                      const float* __restrict__ bias,
                                                      const float* __restrict__ rowscale,
                                                      u16* __restrict__ Ch,
                                                      float* __restrict__ C) {
    __shared__ u16 cols[32 * ELLCAP];                 // 4 KB
    __shared__ __align__(16) u16 gs[32 * K];          // 16 KB (K=256) / 8 KB (K=128)
    __shared__ __align__(16) u16 Bs[2][256 * 32];     // 2 x 16 KB, [n][32k] row-major per q-block
    const int node0 = blockIdx.x * 32;
    const int tid = threadIdx.x;
    *(u16x8*)&cols[tid * 8] = *(const u16x8*)&ell_col[(size_t)node0 * ELLCAP + tid * 8];
    const int nd = tid >> 3, sub = tid & 7;
    const int node = node0 + nd;
    int c = cnt[node]; c = c < ELLCAP ? c : ELLCAP;
    const float dd = dinv[node];
    const int wave = tid >> 6, lane = tid & 63;
    const int r4 = lane >> 2, ch = lane & 3;          // staging: 16 rows x 4 chunks per wave-q
    constexpr int S = K / 32;                          // 32-k tiles
    __syncthreads();                                   // cols staged
    const u16* cl = &cols[nd * ELLCAP];
    const int nb = (c + 7) >> 3;                       // 8-batches (last masked)

    // early stage of tile 0 into buf 0 — no barrier until after the gather,
    // so these loads are fully hidden under it.
    #pragma unroll
    for (int q = 0; q < 4; ++q) {
        int rl = wave * 64 + q * 16 + r4;              // B row (n), 0..255
        gl_lds16(B + (size_t)rl * K + ((ch ^ (r4 & 3)) << 3), &Bs[0][(wave * 4 + q) * 512]);
    }

    // ---- phase 1: aggregate into gs (R6 verbatim) ----
    #pragma unroll 1
    for (int p = 0; p < K / 64; ++p) {
        const int f = p * 64 + sub * 8;
        f32x4 a0 = {}, a1 = {};
        {   // self loop (pre-scaled)
            u16x8 sv = *(const u16x8*)(hs + (size_t)node * K + f);
            #pragma unroll
            for (int i = 0; i < 4; ++i) a0[i] += h2f(sv[i]);
            #pragma unroll
            for (int i = 0; i < 4; ++i) a1[i] += h2f(sv[i + 4]);
        }
        if (nb > 0) {
            u16x8 vbuf[8];
            u16x8 cc = *(const u16x8*)&cl[0];
            #pragma unroll
            for (int j = 0; j < 8; ++j) vbuf[j] = *(const u16x8*)(hs + (size_t)cc[j] * K + f);
            int base = 0;
            for (int b = 1; b < nb; ++b) {
                u16x8 cn = *(const u16x8*)&cl[b * 8];
                u16x8 vn[8];
                #pragma unroll
                for (int j = 0; j < 8; ++j) vn[j] = *(const u16x8*)(hs + (size_t)cn[j] * K + f);
                #pragma unroll
                for (int j = 0; j < 8; ++j) {
                    #pragma unroll
                    for (int i = 0; i < 4; ++i) a0[i] += h2f(vbuf[j][i]);
                    #pragma unroll
                    for (int i = 0; i < 4; ++i) a1[i] += h2f(vbuf[j][i + 4]);
                }
                base += 8;
                #pragma unroll
                for (int j = 0; j < 8; ++j) vbuf[j] = vn[j];
            }
            const u16x8 zz = {};
            #pragma unroll
            for (int j = 0; j < 8; ++j) {
                u16x8 v = (base + j < c) ? vbuf[j] : zz;   // masked final batch
                #pragma unroll
                for (int i = 0; i < 4; ++i) a0[i] += h2f(v[i]);
                #pragma unroll
                for (int i = 0; i < 4; ++i) a1[i] += h2f(v[i + 4]);
            }
        }
        u16x8 o;
        #pragma unroll
        for (int i = 0; i < 4; ++i) o[i] = f2h(a0[i] * dd);
        #pragma unroll
        for (int i = 0; i < 4; ++i) o[i + 4] = f2h(a1[i] * dd);
        const int cc_ = p * 8 + sub;                   // global 8-elem chunk index
        *(u16x8*)&gs[nd * K + ((cc_ ^ (nd & 7)) << 3)] = o;
    }

    // ---- phase 2: GEMM with overlapped double-buffered staging ----
    f32x4 acc[2][4] = {};
    #pragma unroll
    for (int k = 0; k < S; ++k) {
        __syncthreads();   // drains: buf[k&1] loads (overlapped w/ MFMA(k-1) or gather),
                           // gs ds_writes (k==0), and all reads of buf[(k+1)&1] from MFMA(k-1)
        if (k + 1 < S) {   // stage next tile into the idle buffer; flies under MFMA(k)
            #pragma unroll
            for (int q = 0; q < 4; ++q) {
                int rl = wave * 64 + q * 16 + r4;
                gl_lds16(B + (size_t)rl * K + (k + 1) * 32 + ((ch ^ (r4 & 3)) << 3),
                         &Bs[(k + 1) & 1][(wave * 4 + q) * 512]);
            }
        }
        const u16* Bk = Bs[k & 1];
        const int c8 = lane >> 4;                      // 8-elem chunk within 32-k tile, 0..3
        f16x8 bf[4];
        #pragma unroll
        for (int nt = 0; nt < 4; ++nt) {
            int n = wave * 64 + nt * 16 + (lane & 15);
            bf[nt] = *(const f16x8*)&Bk[(wave * 4 + nt) * 512 + (((n & 15) * 4 + (c8 ^ (n & 3))) << 3)];
        }
        #pragma unroll
        for (int mt = 0; mt < 2; ++mt) {
            int ml = mt * 16 + (lane & 15);
            int cg = k * 4 + c8;                       // global chunk index (== R6's k*8+kk*4+..)
            f16x8 af = *(const f16x8*)&gs[ml * K + ((cg ^ (ml & 7)) << 3)];
            #pragma unroll
            for (int nt = 0; nt < 4; ++nt)
                acc[mt][nt] = __builtin_amdgcn_mfma_f32_16x16x32_f16(af, bf[nt], acc[mt][nt], 0, 0, 0);
        }
    }
    // ---- epilogue: bias + relu (+ rowscale); direct stores (R6 verbatim) ----
    // C/D layout col=lane&15, row=(lane>>4)*4+r.
    #pragma unroll
    for (int mt = 0; mt < 2; ++mt) {
        int gr = node0 + mt * 16 + ((lane >> 4) << 2);
        #pragma unroll
        for (int r = 0; r < 4; ++r) {
            float sc = rowscale ? rowscale[gr + r] : 1.f;
            #pragma unroll
            for (int nt = 0; nt < 4; ++nt) {
                int gc = wave * 64 + nt * 16 + (lane & 15);
                float v = sc * fmaxf(acc[mt][nt][r] + bias[gc], 0.f);
                if (Ch) Ch[(size_t)(gr + r) * HID + gc] = f2h(v);
                else    C[(size_t)(gr + r) * HID + gc] = v;
            }
        }
    }
}

// ---------------- pooling ----------------
#define POOL_CHUNK 32
__global__ __launch_bounds__(256) void pool_kernel(const float* __restrict__ h,
                                                   const int* __restrict__ batch,
                                                   float* __restrict__ pool_sum) {
    int f = threadIdx.x;
    int start = blockIdx.x * POOL_CHUNK;
    int end = start + POOL_CHUNK; end = end < N_NODES ? end : N_NODES;
    if (start >= N_NODES) return;
    int gcur = batch[start];
    float acc = 0.f;
    for (int i = start; i < end; ++i) {
        int g = batch[i];
        if (g != gcur) { atomicAdd(&pool_sum[gcur * HID + f], acc); acc = 0.f; gcur = g; }
        acc += h[(size_t)i * HID + f];
    }
    atomicAdd(&pool_sum[gcur * HID + f], acc);
}

__device__ int lb_int(const int* __restrict__ a, int n, int v) {
    int lo = 0, hi = n;
    while (lo < hi) {
        int mid = (lo + hi) >> 1;
        if (a[mid] < v) lo = mid + 1; else hi = mid;
    }
    return lo;
}

__global__ void final_linear_kernel(const float* __restrict__ pool_sum,
                                    const int* __restrict__ batch,
                                    const float* __restrict__ Wlin,
                                    const float* __restrict__ blin,
                                    float* __restrict__ out) {
    int idx = blockIdx.x * blockDim.x + threadIdx.x;
    if (idx >= N_GRAPHS * OUT_F) return;
    int g = idx / OUT_F, o = idx % OUT_F;
    int lo = lb_int(batch, N_NODES, g);
    int hi = lb_int(batch, N_NODES, g + 1);
    float cinv = 1.f / fmaxf((float)(hi - lo), 1.f);
    float s = blin[o];
    for (int k = 0; k < HID; ++k) s += (pool_sum[g * HID + k] * cinv) * Wlin[k * OUT_F + o];
    out[idx] = s;
}

// ---------------- launch ----------------
static inline size_t align_up(size_t x, size_t a) { return (x + a - 1) & ~(a - 1); }

extern "C" void kernel_launch(void* const* d_in, const int* in_sizes, int n_in,
                              void* d_out, int out_size, void* d_ws, size_t ws_size,
                              hipStream_t stream) {
    const float* x     = (const float*)d_in[0];
    const int*   elist = (const int*)d_in[1];   // [2, E]
    const int*   batch = (const int*)d_in[2];
    const float* W1    = (const float*)d_in[3];
    const float* b1    = (const float*)d_in[4];
    const float* Wm    = (const float*)d_in[5];
    const float* bm    = (const float*)d_in[6];
    const float* Wlin  = (const float*)d_in[7];
    const float* blin  = (const float*)d_in[8];
    float* outp = (float*)d_out;

    const int* srcA = elist;
    const int* dstA = elist + N_EDGES;

    char* ws = (char*)d_ws;
    size_t off = 0;
    float* h      = (float*)(ws + off); off = align_up(off + sizeof(float) * N_NODES * HID, 1024);
    u16*   hA     = (u16*)(ws + off);   off = align_up(off + sizeof(u16) * N_NODES * HID, 1024);
    u16*   hB     = (u16*)(ws + off);   off = align_up(off + sizeof(u16) * N_NODES * HID, 1024);
    u16*   xs     = (u16*)(ws + off);   off = align_up(off + sizeof(u16) * N_NODES * F_IN, 1024);
    u16*   W1T    = (u16*)(ws + off);   off = align_up(off + sizeof(u16) * F_IN * HID, 1024);
    u16*   WmT    = (u16*)(ws + off);   off = align_up(off + sizeof(u16) * (N_LAYERS - 1) * HID * HID, 1024);
    int*   cursor = (int*)(ws + off);   off = align_up(off + sizeof(int) * N_NODES, 1024);
    float* dinv   = (float*)(ws + off); off = align_up(off + sizeof(float) * N_NODES, 1024);
    u16*   ell_col = (u16*)(ws + off);  off = align_up(off + sizeof(u16) * N_NODES * ELLCAP, 1024);
    float* pool_sum = (float*)(ws + off); off = align_up(off + sizeof(float) * N_GRAPHS * HID, 1024);

    hipMemsetAsync(cursor, 0, sizeof(int) * N_NODES, stream);
    hipMemsetAsync(ell_col, 0, sizeof(u16) * N_NODES * ELLCAP, stream);  // pad slots -> node 0 (masked)
    hipMemsetAsync(pool_sum, 0, sizeof(float) * N_GRAPHS * HID, stream);

    fill_ell_kernel<<<(N_EDGES + 255) / 256, 256, 0, stream>>>(srcA, dstA, cursor, ell_col, N_EDGES);
    dinv_kernel<<<(N_NODES + 255) / 256, 256, 0, stream>>>(cursor, dinv, N_NODES);
    prescale_x_kernel<<<(N_NODES * F_IN + 255) / 256, 256, 0, stream>>>(x, cursor, xs, N_NODES * F_IN);

    transpose_f16_tiled<<<dim3((F_IN / 32) * (HID / 32), 1), 256, 0, stream>>>(W1, W1T, F_IN, HID);
    transpose_f16_tiled<<<dim3((HID / 32) * (HID / 32), N_LAYERS - 1), 256, 0, stream>>>(Wm, WmT, HID, HID);

    const int lgrid = N_NODES / 32;   // 625, exact
    // layer 1: K = F_IN, gather from xs, write fp16 hA (double-buffer ping-pong after)
    layer_fused<F_IN><<<lgrid, 256, 0, stream>>>(xs, W1T, ell_col, cursor, dinv, b1, dinv, hA, h);
    u16* cur = hA; u16* nxt = hB;
    for (int l = 0; l < N_LAYERS - 1; ++l) {
        const bool last = (l == N_LAYERS - 2);
        layer_fused<HID><<<lgrid, 256, 0, stream>>>(cur, WmT + (size_t)l * HID * HID,
                                                    ell_col, cursor, dinv,
                                                    bm + (size_t)l * HID,
                                                    last ? nullptr : dinv,
                                                    last ? nullptr : nxt, h);
        u16* t = cur; cur = nxt; nxt = t;
    }
    pool_kernel<<<(N_NODES + POOL_CHUNK - 1) / POOL_CHUNK, 256, 0, stream>>>(h, batch, pool_sum);
    final_linear_kernel<<<2, 256, 0, stream>>>(pool_sum, batch, Wlin, blin, outp);
}

// Round 13
// 898.424 us; speedup vs baseline: 1.2015x; 1.0602x over previous
//
#include <hip/hip_runtime.h>

typedef unsigned short u16;
typedef unsigned int u32;
typedef __attribute__((ext_vector_type(8))) _Float16 f16x8;  // 8 fp16 = 4 VGPRs
typedef __attribute__((ext_vector_type(4))) float f32x4;
typedef __attribute__((ext_vector_type(8))) u16 u16x8;

#define N_NODES 20000
#define N_EDGES 320000
#define F_IN 128
#define HID 256
#define OUT_F 32
#define N_LAYERS 30
#define N_GRAPHS 16
#define ELLCAP 64

// ---------------- fp16 helpers ----------------
__device__ __forceinline__ float h2f(u16 u) {
    _Float16 h;
    __builtin_memcpy(&h, &u, 2);
    return (float)h;
}
__device__ __forceinline__ u16 f2h(float f) {
    _Float16 h = (_Float16)f;
    u16 u;
    __builtin_memcpy(&u, &h, 2);
    return u;
}

__device__ __forceinline__ void gl_lds16(const u16* g, u16* l) {
    __builtin_amdgcn_global_load_lds((const u32*)g, (u32*)l, 16, 0, 0);
}

// ---------------- graph build ----------------
// fill_ell also produces the degree: cursor's final value == in-degree at dst.
// ell_col is pre-zeroed; unfilled slots stay 0 (node 0: valid, masked off in agg).
__global__ void fill_ell_kernel(const int* __restrict__ src, const int* __restrict__ dst,
                                int* __restrict__ cursor, u16* __restrict__ ell_col, int E) {
    int e = blockIdx.x * blockDim.x + threadIdx.x;
    if (e >= E) return;
    int s = src[e], d = dst[e];
    int slot = atomicAdd(&cursor[d], 1);
    if (slot < ELLCAP) ell_col[d * ELLCAP + slot] = (u16)s;
}

__global__ void dinv_kernel(const int* __restrict__ cnt, float* __restrict__ dinv, int n) {
    int i = blockIdx.x * blockDim.x + threadIdx.x;
    if (i < n) dinv[i] = rsqrtf((float)(cnt[i] + 1));  // +1 self loop
}

// x' = fp16(dinv ⊙ x): layer-1 gather source (fp16 = the measured numerics floor;
// fp8 failed at 9.3e-6 vs threshold 1.86e-7, R4)
__global__ void prescale_x_kernel(const float* __restrict__ x, const int* __restrict__ cnt,
                                  u16* __restrict__ xs, int total) {
    int i = blockIdx.x * 256 + threadIdx.x;
    if (i < total) xs[i] = f2h(x[i] * rsqrtf((float)(cnt[i >> 7] + 1)));   // F_IN = 128
}

// ---------------- weight transpose to fp16 (LDS-tiled, coalesced writes) ----------------
// W [L][K][N] (f32) -> T [L][N][K] (fp16); 32x32 tiles.
__global__ __launch_bounds__(256) void transpose_f16_tiled(const float* __restrict__ W,
                                                           u16* __restrict__ T,
                                                           int K, int N) {
    __shared__ float tile[32][33];
    const int l = blockIdx.y;
    const int ntn = N >> 5;
    const int kt = blockIdx.x / ntn, ntile = blockIdx.x % ntn;
    const float* Wl = W + (size_t)l * K * N;
    u16* Tl = T + (size_t)l * K * N;
    const int r8 = threadIdx.x >> 5, c = threadIdx.x & 31;
    #pragma unroll
    for (int rr = 0; rr < 4; ++rr) {
        int r = rr * 8 + r8;
        tile[r][c] = Wl[(size_t)(kt * 32 + r) * N + ntile * 32 + c];
    }
    __syncthreads();
    #pragma unroll
    for (int rr = 0; rr < 4; ++rr) {
        int n = rr * 8 + r8;                 // transposed row (N dim)
        float v = tile[c][n];                // W[k=kt*32+c][n]
        Tl[(size_t)(ntile * 32 + n) * K + kt * 32 + c] = f2h(v);
    }
}

// ---------------- fused layer (R13 = R6 verbatim + pool fused into last-layer epilogue) ----------------
// One kernel per GCN layer. Block = 32 nodes, 256 threads (4 waves). Grid = 625.
// Lineage (measured): R6 bulk = 930.9 BEST. All intra-layer restructures failed or
// neutral: R7 interleave +370, R9 direct-B +147, R10 degree-sort +148 (divergence
// null), R11 cooperative rejected under graph capture, R12 Bs-dbuf +22 (neutral).
// Floor diagnosis: gather is L3 line-touch-rate bound (h 10.2MB > 4MiB/XCD L2;
// fp16 = numerics floor -> E x 4 touches/layer irreducible).
// R13's only change: last layer (Ch==nullptr) stages the f32 tile in LDS (Bs
// reused, 32KB exact) and reduces mean-pool contributions per column over the
// block's 32 sorted-batch rows -> one atomicAdd per (graph,col) segment. Removes
// the h f32 buffer (20.5MB write + read) and the pool_kernel dispatch.
// NUMERICS: layers 1..29 bit-identical to R6; pool order changes ulp-level only.
template <int K>
__global__ __launch_bounds__(256, 3) void layer_fused(const u16* __restrict__ hs,
                                                      const u16* __restrict__ B,
                                                      const u16* __restrict__ ell_col,
                                                      const int* __restrict__ cnt,
                                                      const float* __restrict__ dinv,
                                                      const float* __restrict__ bias,
                                                      const float* __restrict__ rowscale,
                                                      const int* __restrict__ batch,
                                                      u16* __restrict__ Ch,
                                                      float* __restrict__ pool_sum) {
    __shared__ u16 cols[32 * ELLCAP];                 // 4 KB
    __shared__ __align__(16) u16 gs[32 * K];          // 16 KB (K=256) / 8 KB (K=128)
    __shared__ __align__(16) u16 Bs[64 * 64 * 4];     // 32 KB: B n-major [256][64k]; last layer: f32 out-stage
    const int node0 = blockIdx.x * 32;
    const int tid = threadIdx.x;
    *(u16x8*)&cols[tid * 8] = *(const u16x8*)&ell_col[(size_t)node0 * ELLCAP + tid * 8];
    const int nd = tid >> 3, sub = tid & 7;
    const int node = node0 + nd;
    int c = cnt[node]; c = c < ELLCAP ? c : ELLCAP;
    const float dd = dinv[node];
    __syncthreads();                                   // cols staged
    const u16* cl = &cols[nd * ELLCAP];
    const int nb = (c + 7) >> 3;                       // 8-batches (last masked)
    constexpr int S = K / 64;

    // ---- phase 1: aggregate into gs (R6 verbatim) ----
    #pragma unroll 1
    for (int p = 0; p < S; ++p) {
        const int f = p * 64 + sub * 8;
        f32x4 a0 = {}, a1 = {};
        {   // self loop (pre-scaled)
            u16x8 sv = *(const u16x8*)(hs + (size_t)node * K + f);
            #pragma unroll
            for (int i = 0; i < 4; ++i) a0[i] += h2f(sv[i]);
            #pragma unroll
            for (int i = 0; i < 4; ++i) a1[i] += h2f(sv[i + 4]);
        }
        if (nb > 0) {
            u16x8 vbuf[8];
            u16x8 cc = *(const u16x8*)&cl[0];
            #pragma unroll
            for (int j = 0; j < 8; ++j) vbuf[j] = *(const u16x8*)(hs + (size_t)cc[j] * K + f);
            int base = 0;
            for (int b = 1; b < nb; ++b) {
                u16x8 cn = *(const u16x8*)&cl[b * 8];
                u16x8 vn[8];
                #pragma unroll
                for (int j = 0; j < 8; ++j) vn[j] = *(const u16x8*)(hs + (size_t)cn[j] * K + f);
                #pragma unroll
                for (int j = 0; j < 8; ++j) {
                    #pragma unroll
                    for (int i = 0; i < 4; ++i) a0[i] += h2f(vbuf[j][i]);
                    #pragma unroll
                    for (int i = 0; i < 4; ++i) a1[i] += h2f(vbuf[j][i + 4]);
                }
                base += 8;
                #pragma unroll
                for (int j = 0; j < 8; ++j) vbuf[j] = vn[j];
            }
            const u16x8 zz = {};
            #pragma unroll
            for (int j = 0; j < 8; ++j) {
                u16x8 v = (base + j < c) ? vbuf[j] : zz;   // masked final batch
                #pragma unroll
                for (int i = 0; i < 4; ++i) a0[i] += h2f(v[i]);
                #pragma unroll
                for (int i = 0; i < 4; ++i) a1[i] += h2f(v[i + 4]);
            }
        }
        u16x8 o;
        #pragma unroll
        for (int i = 0; i < 4; ++i) o[i] = f2h(a0[i] * dd);
        #pragma unroll
        for (int i = 0; i < 4; ++i) o[i + 4] = f2h(a1[i] * dd);
        const int cc_ = p * 8 + sub;                   // global 8-elem chunk index
        *(u16x8*)&gs[nd * K + ((cc_ ^ (nd & 7)) << 3)] = o;
    }

    // ---- phase 2: GEMM (R6 verbatim: Bs staged via global_load_lds) ----
    const int wave = tid >> 6, lane = tid & 63;
    const int lr = lane >> 3, lc = lane & 7;
    #pragma unroll
    for (int q = 0; q < 8; ++q) {
        int rl = (wave * 8 + q) * 8 + lr;              // B row (n), 0..255
        gl_lds16(B + (size_t)rl * K + ((lc ^ (rl & 7)) << 3), &Bs[(wave * 8 + q) * 512]);
    }
    f32x4 acc[2][4] = {};
    #pragma unroll
    for (int k = 0; k < S; ++k) {
        __syncthreads();                               // gs + Bs(k) ready (drains vmcnt)
        const int k0 = k * 64;
        #pragma unroll
        for (int kk = 0; kk < 2; ++kk) {
            const int c8 = kk * 4 + (lane >> 4);       // chunk within 64-k tile, 0..7
            f16x8 bf[4];
            #pragma unroll
            for (int nt = 0; nt < 4; ++nt) {
                int n = wave * 64 + nt * 16 + (lane & 15);
                bf[nt] = *(const f16x8*)&Bs[n * 64 + ((c8 ^ (n & 7)) << 3)];
            }
            #pragma unroll
            for (int mt = 0; mt < 2; ++mt) {
                int ml = mt * 16 + (lane & 15);
                int cg = (k0 >> 3) + c8;               // global chunk index
                f16x8 af = *(const f16x8*)&gs[ml * K + ((cg ^ (ml & 7)) << 3)];
                #pragma unroll
                for (int nt = 0; nt < 4; ++nt)
                    acc[mt][nt] = __builtin_amdgcn_mfma_f32_16x16x32_f16(af, bf[nt], acc[mt][nt], 0, 0, 0);
            }
        }
        if (k + 1 < S) {
            __syncthreads();                           // all waves done reading Bs(k)
            const int kn = k0 + 64;
            #pragma unroll
            for (int q = 0; q < 8; ++q) {
                int rl = (wave * 8 + q) * 8 + lr;
                gl_lds16(B + (size_t)rl * K + kn + ((lc ^ (rl & 7)) << 3), &Bs[(wave * 8 + q) * 512]);
            }
        }
    }
    // ---- epilogue ----
    // C/D layout col=lane&15, row=(lane>>4)*4+r. Values identical to R6.
    if (Ch) {
        // middle layers: direct fp16 stores (R6 verbatim)
        #pragma unroll
        for (int mt = 0; mt < 2; ++mt) {
            int gr = node0 + mt * 16 + ((lane >> 4) << 2);
            #pragma unroll
            for (int r = 0; r < 4; ++r) {
                float sc = rowscale ? rowscale[gr + r] : 1.f;
                #pragma unroll
                for (int nt = 0; nt < 4; ++nt) {
                    int gc = wave * 64 + nt * 16 + (lane & 15);
                    float v = sc * fmaxf(acc[mt][nt][r] + bias[gc], 0.f);
                    Ch[(size_t)(gr + r) * HID + gc] = f2h(v);
                }
            }
        }
    } else {
        // LAST layer: fused mean-pool contribution. Stage f32 tile in Bs (32KB
        // exact), reduce over sorted-batch row segments, one atomicAdd per
        // (graph,col) segment per block.
        __syncthreads();                               // all GEMM reads of gs/Bs done
        float* Bf = (float*)Bs;                        // 32 x 256 f32
        #pragma unroll
        for (int mt = 0; mt < 2; ++mt) {
            #pragma unroll
            for (int r = 0; r < 4; ++r) {
                int lrow = mt * 16 + ((lane >> 4) << 2) + r;
                #pragma unroll
                for (int nt = 0; nt < 4; ++nt) {
                    int gc = wave * 64 + nt * 16 + (lane & 15);
                    float v = fmaxf(acc[mt][nt][r] + bias[gc], 0.f);
                    Bf[lrow * HID + (gc ^ ((lrow & 7) << 2))] = v;
                }
            }
        }
        __syncthreads();
        const int col = tid;                           // 256 threads = 256 cols
        int gcur = batch[node0];
        float a = 0.f;
        #pragma unroll 1
        for (int i = 0; i < 32; ++i) {
            int g = batch[node0 + i];                  // sorted; broadcast read
            if (g != gcur) { atomicAdd(&pool_sum[gcur * HID + col], a); a = 0.f; gcur = g; }
            a += Bf[i * HID + (col ^ ((i & 7) << 2))];
        }
        atomicAdd(&pool_sum[gcur * HID + col], a);
    }
}

__device__ int lb_int(const int* __restrict__ a, int n, int v) {
    int lo = 0, hi = n;
    while (lo < hi) {
        int mid = (lo + hi) >> 1;
        if (a[mid] < v) lo = mid + 1; else hi = mid;
    }
    return lo;
}

__global__ void final_linear_kernel(const float* __restrict__ pool_sum,
                                    const int* __restrict__ batch,
                                    const float* __restrict__ Wlin,
                                    const float* __restrict__ blin,
                                    float* __restrict__ out) {
    int idx = blockIdx.x * blockDim.x + threadIdx.x;
    if (idx >= N_GRAPHS * OUT_F) return;
    int g = idx / OUT_F, o = idx % OUT_F;
    int lo = lb_int(batch, N_NODES, g);
    int hi = lb_int(batch, N_NODES, g + 1);
    float cinv = 1.f / fmaxf((float)(hi - lo), 1.f);
    float s = blin[o];
    for (int k = 0; k < HID; ++k) s += (pool_sum[g * HID + k] * cinv) * Wlin[k * OUT_F + o];
    out[idx] = s;
}

// ---------------- launch ----------------
static inline size_t align_up(size_t x, size_t a) { return (x + a - 1) & ~(a - 1); }

extern "C" void kernel_launch(void* const* d_in, const int* in_sizes, int n_in,
                              void* d_out, int out_size, void* d_ws, size_t ws_size,
                              hipStream_t stream) {
    const float* x     = (const float*)d_in[0];
    const int*   elist = (const int*)d_in[1];   // [2, E]
    const int*   batch = (const int*)d_in[2];
    const float* W1    = (const float*)d_in[3];
    const float* b1    = (const float*)d_in[4];
    const float* Wm    = (const float*)d_in[5];
    const float* bm    = (const float*)d_in[6];
    const float* Wlin  = (const float*)d_in[7];
    const float* blin  = (const float*)d_in[8];
    float* outp = (float*)d_out;

    const int* srcA = elist;
    const int* dstA = elist + N_EDGES;

    char* ws = (char*)d_ws;
    size_t off = 0;
    u16*   hA     = (u16*)(ws + off);   off = align_up(off + sizeof(u16) * N_NODES * HID, 1024);
    u16*   hB     = (u16*)(ws + off);   off = align_up(off + sizeof(u16) * N_NODES * HID, 1024);
    u16*   xs     = (u16*)(ws + off);   off = align_up(off + sizeof(u16) * N_NODES * F_IN, 1024);
    u16*   W1T    = (u16*)(ws + off);   off = align_up(off + sizeof(u16) * F_IN * HID, 1024);
    u16*   WmT    = (u16*)(ws + off);   off = align_up(off + sizeof(u16) * (N_LAYERS - 1) * HID * HID, 1024);
    int*   cursor = (int*)(ws + off);   off = align_up(off + sizeof(int) * N_NODES, 1024);
    float* dinv   = (float*)(ws + off); off = align_up(off + sizeof(float) * N_NODES, 1024);
    u16*   ell_col = (u16*)(ws + off);  off = align_up(off + sizeof(u16) * N_NODES * ELLCAP, 1024);
    float* pool_sum = (float*)(ws + off); off = align_up(off + sizeof(float) * N_GRAPHS * HID, 1024);

    hipMemsetAsync(cursor, 0, sizeof(int) * N_NODES, stream);
    hipMemsetAsync(ell_col, 0, sizeof(u16) * N_NODES * ELLCAP, stream);  // pad slots -> node 0 (masked)
    hipMemsetAsync(pool_sum, 0, sizeof(float) * N_GRAPHS * HID, stream);

    fill_ell_kernel<<<(N_EDGES + 255) / 256, 256, 0, stream>>>(srcA, dstA, cursor, ell_col, N_EDGES);
    dinv_kernel<<<(N_NODES + 255) / 256, 256, 0, stream>>>(cursor, dinv, N_NODES);
    prescale_x_kernel<<<(N_NODES * F_IN + 255) / 256, 256, 0, stream>>>(x, cursor, xs, N_NODES * F_IN);

    transpose_f16_tiled<<<dim3((F_IN / 32) * (HID / 32), 1), 256, 0, stream>>>(W1, W1T, F_IN, HID);
    transpose_f16_tiled<<<dim3((HID / 32) * (HID / 32), N_LAYERS - 1), 256, 0, stream>>>(Wm, WmT, HID, HID);

    const int lgrid = N_NODES / 32;   // 625, exact
    // layer 1: K = F_IN, gather from xs, write fp16 hA (double-buffer ping-pong after)
    layer_fused<F_IN><<<lgrid, 256, 0, stream>>>(xs, W1T, ell_col, cursor, dinv, b1, dinv,
                                                 batch, hA, pool_sum);
    u16* cur = hA; u16* nxt = hB;
    for (int l = 0; l < N_LAYERS - 1; ++l) {
        const bool last = (l == N_LAYERS - 2);
        layer_fused<HID><<<lgrid, 256, 0, stream>>>(cur, WmT + (size_t)l * HID * HID,
                                                    ell_col, cursor, dinv,
                                                    bm + (size_t)l * HID,
                                                    last ? nullptr : dinv,
                                                    batch,
                                                    last ? nullptr : nxt, pool_sum);
        u16* t = cur; cur = nxt; nxt = t;
    }
    final_linear_kernel<<<2, 256, 0, stream>>>(pool_sum, batch, Wlin, blin, outp);
}